// Round 12
// baseline (1904.785 us; speedup 1.0000x reference)
//
#include <hip/hip_runtime.h>
#include <math.h>

#define B_  1024
#define N_  16
#define I_  256
#define H_  1024
#define H3_ 3072

typedef _Float16 f16;
typedef _Float16 f16x4 __attribute__((ext_vector_type(4)));
typedef _Float16 f16x8 __attribute__((ext_vector_type(8)));
typedef float    f32x4 __attribute__((ext_vector_type(4)));

__device__ __forceinline__ float sigmoidf_(float x) { return 1.f / (1.f + expf(-x)); }

// LDS layout (verified r3): row = 64B = 4 groups of 16B; group g holds
// k = {4g..4g+3, 16+4g..16+4g+3}; XOR swizzle by ((row>>1)&3).
__device__ __forceinline__ void lds_write_row(f16* dst, int row, int s, f16x8 vv)
{
    int key = (row >> 1) & 3;
    int g0  = (((s & 1) * 2 + 0) ^ key);
    int g1  = (((s & 1) * 2 + 1) ^ key);
    f16x4 lo = {vv[0], vv[1], vv[2], vv[3]};
    f16x4 hi = {vv[4], vv[5], vv[6], vv[7]};
    *(f16x4*)((char*)dst + row * 64 + g0 * 16 + (s >> 1) * 8) = lo;
    *(f16x4*)((char*)dst + row * 64 + g1 * 16 + (s >> 1) * 8) = hi;
}

// ---------------------------------------------------------------------------
// Precompute t_gate (17,B) and idx_seq (B,N)
// ---------------------------------------------------------------------------
__global__ void precompute_kernel(const float* __restrict__ phis,
                                  float* __restrict__ tg,
                                  int* __restrict__ idx)
{
    int b = blockIdx.x * blockDim.x + threadIdx.x;
    if (b >= B_) return;
    tg[b] = 1.0f;
    for (int t = 1; t < N_; ++t)
        tg[t * B_ + b] = phis[(size_t)b * N_ * N_ + t * N_ + (t - 1)];
    tg[16 * B_ + b] = 0.0f;
    for (int t = 0; t < N_; ++t) {
        float ns = 0.f;
        for (int k = 0; k < N_; ++k) ns += phis[(size_t)b * N_ * N_ + t * N_ + k];
        int nsi = (int)(ns + 0.5f);
        idx[b * N_ + t] = (nsi + t - 1) % N_;
    }
}

// ---------------------------------------------------------------------------
// Casts
// ---------------------------------------------------------------------------
__global__ void cast_kernel(const float* __restrict__ in, f16* __restrict__ out, int n)
{
    int i = blockIdx.x * blockDim.x + threadIdx.x;
    if (i < n) out[i] = (f16)in[i];
}

__global__ void cast4_kernel(const float* __restrict__ s0, f16* __restrict__ d0, int n0,
                             const float* __restrict__ s1, f16* __restrict__ d1, int n1,
                             const float* __restrict__ s2, f16* __restrict__ d2, int n2,
                             const float* __restrict__ s3, f16* __restrict__ d3, int n3)
{
    int i = blockIdx.x * blockDim.x + threadIdx.x;
    int T0 = n0, T1 = T0 + n1, T2 = T1 + n2, T3 = T2 + n3;
    if (i < T0) d0[i] = (f16)s0[i];
    else if (i < T1) d1[i - T0] = (f16)s1[i - T0];
    else if (i < T2) d2[i - T1] = (f16)s2[i - T1];
    else if (i < T3) d3[i - T2] = (f16)s3[i - T2];
}

__global__ __launch_bounds__(256) void transpose_cast2_kernel(
    const float* __restrict__ in0, f16* __restrict__ out0,
    const float* __restrict__ in1, f16* __restrict__ out1)
{
    const float* in  = blockIdx.z ? in1 : in0;
    f16*        outp = blockIdx.z ? out1 : out0;
    __shared__ float tile[32][33];
    int bx = blockIdx.x * 32, by = blockIdx.y * 32;
    int tx = threadIdx.x & 31, ty = threadIdx.x >> 5;
#pragma unroll
    for (int r = 0; r < 32; r += 8)
        tile[ty + r][tx] = in[(size_t)(by + ty + r) * H_ + bx + tx];
    __syncthreads();
#pragma unroll
    for (int r = 0; r < 32; r += 8)
        outp[(size_t)(bx + ty + r) * H_ + by + tx] = (f16)tile[tx][ty + r];
}

// ---------------------------------------------------------------------------
// 128x128 MFMA GEMM (W1xe): C = A @ Bt^T, f16 out, XCD-chunked swizzle.
// 2-deep prefetch pipeline: two register sets, dbuf LDS.
// ---------------------------------------------------------------------------
template <typename OutT>
__global__ __launch_bounds__(256) void hgemm_kernel(
    const f16* __restrict__ A, int lda,
    const f16* __restrict__ Bt, int ldb,
    OutT* __restrict__ C, int ldc, int K)
{
    __shared__ char smem[32768];   // As[2]@0/8192, Bs[2]@16384/24576

    const int tid  = threadIdx.x;
    const int lane = tid & 63;
    const int wid  = tid >> 6;
    const int wr   = wid >> 1;
    const int wc   = wid & 1;
    const int rsel = lane & 15;
    const int kb   = lane >> 4;

    int flat = blockIdx.y * gridDim.x + blockIdx.x;
    int nwg  = gridDim.x * gridDim.y;
    int cpx  = nwg >> 3;
    int nf   = (flat & 7) * cpx + (flat >> 3);
    const int n0 = (int)(nf % gridDim.x) * 128;
    const int m0 = (int)(nf / gridDim.x) * 128;

    const int strow0 = tid >> 2;
    const int strow1 = 64 + (tid >> 2);
    const int sts    = tid & 3;

    f32x4 acc[4][4];
#pragma unroll
    for (int m = 0; m < 4; ++m)
#pragma unroll
        for (int n = 0; n < 4; ++n) acc[m][n] = (f32x4)0.f;

    f16x8 sA0, sA1, sB0, sB1;   // set 0
    f16x8 tA0, tA1, tB0, tB1;   // set 1
    auto GL0 = [&](int k0) {
        sA0 = *(const f16x8*)(A + (size_t)(m0 + strow0) * lda + k0 + sts * 8);
        sA1 = *(const f16x8*)(A + (size_t)(m0 + strow1) * lda + k0 + sts * 8);
        sB0 = *(const f16x8*)(Bt + (size_t)(n0 + strow0) * ldb + k0 + sts * 8);
        sB1 = *(const f16x8*)(Bt + (size_t)(n0 + strow1) * ldb + k0 + sts * 8);
    };
    auto GL1 = [&](int k0) {
        tA0 = *(const f16x8*)(A + (size_t)(m0 + strow0) * lda + k0 + sts * 8);
        tA1 = *(const f16x8*)(A + (size_t)(m0 + strow1) * lda + k0 + sts * 8);
        tB0 = *(const f16x8*)(Bt + (size_t)(n0 + strow0) * ldb + k0 + sts * 8);
        tB1 = *(const f16x8*)(Bt + (size_t)(n0 + strow1) * ldb + k0 + sts * 8);
    };
    auto LW0 = [&](int c) {
        f16* As_ = (f16*)(smem + c * 8192);
        f16* Bs_ = (f16*)(smem + 16384 + c * 8192);
        lds_write_row(As_, strow0, sts, sA0);
        lds_write_row(As_, strow1, sts, sA1);
        lds_write_row(Bs_, strow0, sts, sB0);
        lds_write_row(Bs_, strow1, sts, sB1);
    };
    auto LW1 = [&](int c) {
        f16* As_ = (f16*)(smem + c * 8192);
        f16* Bs_ = (f16*)(smem + 16384 + c * 8192);
        lds_write_row(As_, strow0, sts, tA0);
        lds_write_row(As_, strow1, sts, tA1);
        lds_write_row(Bs_, strow0, sts, tB0);
        lds_write_row(Bs_, strow1, sts, tB1);
    };
    auto COMP = [&](int c) {
        char* As_ = smem + c * 8192;
        char* Bs_ = smem + 16384 + c * 8192;
        f16x8 af[4], bf[4];
#pragma unroll
        for (int m = 0; m < 4; ++m) {
            int row = wr * 64 + m * 16 + rsel;
            af[m] = *(const f16x8*)(As_ + row * 64 + ((kb ^ ((row >> 1) & 3)) << 4));
        }
#pragma unroll
        for (int n = 0; n < 4; ++n) {
            int row = wc * 64 + n * 16 + rsel;
            bf[n] = *(const f16x8*)(Bs_ + row * 64 + ((kb ^ ((row >> 1) & 3)) << 4));
        }
#pragma unroll
        for (int m = 0; m < 4; ++m)
#pragma unroll
            for (int n = 0; n < 4; ++n)
                acc[m][n] = __builtin_amdgcn_mfma_f32_16x16x32_f16(af[m], bf[n], acc[m][n], 0, 0, 0);
    };

    const int nk = K / 32;   // even
    GL0(0);
    GL1(32);
    LW0(0);
    __syncthreads();

    for (int ks = 0; ks < nk; ks += 2) {
        if (ks + 2 < nk) GL0((ks + 2) * 32);
        COMP(0);
        LW1(1);
        __syncthreads();
        if (ks + 3 < nk) GL1((ks + 3) * 32);
        COMP(1);
        if (ks + 2 < nk) LW0(0);
        __syncthreads();
    }

#pragma unroll
    for (int m = 0; m < 4; ++m) {
        int row0 = m0 + wr * 64 + m * 16 + kb * 4;
#pragma unroll
        for (int n = 0; n < 4; ++n) {
            int col = n0 + wc * 64 + n * 16 + rsel;
#pragma unroll
            for (int r = 0; r < 4; ++r)
                C[(size_t)(row0 + r) * ldc + col] = (OutT)acc[m][n][r];
        }
    }
}

// ---------------------------------------------------------------------------
// Fused GEMM + GRU (32b x 64j, grid 16x32 = 2 blocks/CU), split-K (2 wg).
// UNIFIED 20-tile 2-deep pipeline: both GEMM phases share one pipeline
// (single prologue/drain); tile i<nk0 -> (A1,Bt1,acc1), else (A2,Bt2,acc2).
// NOTE: encoder must pass DIFFERENT buffers for A2 (read) and hs (write) —
// r10 race.
// ---------------------------------------------------------------------------
template <int MODE>
__global__ __launch_bounds__(512) void gru_fused_kernel(
    const f16* __restrict__ A1, int lda1,
    const f16* __restrict__ Bt1, int ldb1, int K1,
    const f16* __restrict__ A2,
    const f16* __restrict__ Bt2,
    const float* __restrict__ bih, const float* __restrict__ bhh,
    float* __restrict__ h,
    const float* __restrict__ tg_cur,
    const float* __restrict__ tg_next,
    f16* __restrict__ out_a,
    f16* __restrict__ hs)
{
    __shared__ char smem[57344];

    const int tid  = threadIdx.x;
    const int wg   = tid >> 8;
    const int ltid = tid & 255;
    const int lane = tid & 63;
    const int wid4 = (ltid >> 6);
    const int wr   = wid4 >> 1;
    const int wc   = wid4 & 1;
    const int rsel = lane & 15;
    const int kb   = lane >> 4;

    char* base = smem + wg * 28672;   // As[c]@ c*2048, Bs[c]@ 4096 + c*12288

    int flat = blockIdx.y * gridDim.x + blockIdx.x;   // grid (16, 32)
    int nf   = (flat & 7) * 64 + (flat >> 3);
    const int j0 = (nf >> 5) * 64;
    const int b0 = (nf & 31) * 32;

    const int strow = ltid >> 2;
    const int sts   = ltid & 3;

    const int nk0 = (K1 >> 1) >> 5;           // 4
    const int NT  = nk0 + ((H_ >> 1) >> 5);   // 20

    f32x4 acc1[3][2], acc2[3][2];
#pragma unroll
    for (int g = 0; g < 3; ++g)
#pragma unroll
        for (int nt = 0; nt < 2; ++nt) { acc1[g][nt] = (f32x4)0.f; acc2[g][nt] = (f32x4)0.f; }

    f16x8 sA, sB0, sB1, sB2;
    f16x8 tA, tB0, tB1, tB2;

    auto srcAddr = [&](int i, const f16*& Aq, const f16*& Bq, int& la, int& lb, int& k0) {
        if (i < nk0) { Aq = A1; Bq = Bt1; la = lda1; lb = ldb1; k0 = wg * (K1 >> 1) + i * 32; }
        else         { Aq = A2; Bq = Bt2; la = H_;   lb = H_;   k0 = wg * (H_ >> 1) + (i - nk0) * 32; }
    };
    auto GL0 = [&](int i) {
        const f16 *Aq, *Bq; int la, lb, k0;
        srcAddr(i, Aq, Bq, la, lb, k0);
        if (ltid < 128) sA = *(const f16x8*)(Aq + (size_t)(b0 + strow) * la + k0 + sts * 8);
        sB0 = *(const f16x8*)(Bq + (size_t)(0 * H_ + j0 + strow) * lb + k0 + sts * 8);
        sB1 = *(const f16x8*)(Bq + (size_t)(1 * H_ + j0 + strow) * lb + k0 + sts * 8);
        sB2 = *(const f16x8*)(Bq + (size_t)(2 * H_ + j0 + strow) * lb + k0 + sts * 8);
    };
    auto GL1 = [&](int i) {
        const f16 *Aq, *Bq; int la, lb, k0;
        srcAddr(i, Aq, Bq, la, lb, k0);
        if (ltid < 128) tA = *(const f16x8*)(Aq + (size_t)(b0 + strow) * la + k0 + sts * 8);
        tB0 = *(const f16x8*)(Bq + (size_t)(0 * H_ + j0 + strow) * lb + k0 + sts * 8);
        tB1 = *(const f16x8*)(Bq + (size_t)(1 * H_ + j0 + strow) * lb + k0 + sts * 8);
        tB2 = *(const f16x8*)(Bq + (size_t)(2 * H_ + j0 + strow) * lb + k0 + sts * 8);
    };
    auto LW0 = [&](int c) {
        if (ltid < 128) lds_write_row((f16*)(base + c * 2048), strow, sts, sA);
        f16* Bs_ = (f16*)(base + 4096 + c * 12288);
        lds_write_row(Bs_ + 0 * 64 * 32, strow, sts, sB0);
        lds_write_row(Bs_ + 1 * 64 * 32, strow, sts, sB1);
        lds_write_row(Bs_ + 2 * 64 * 32, strow, sts, sB2);
    };
    auto LW1 = [&](int c) {
        if (ltid < 128) lds_write_row((f16*)(base + c * 2048), strow, sts, tA);
        f16* Bs_ = (f16*)(base + 4096 + c * 12288);
        lds_write_row(Bs_ + 0 * 64 * 32, strow, sts, tB0);
        lds_write_row(Bs_ + 1 * 64 * 32, strow, sts, tB1);
        lds_write_row(Bs_ + 2 * 64 * 32, strow, sts, tB2);
    };
    auto COMP = [&](int c, int ph) {
        char* As_ = base + c * 2048;
        char* Bs_ = base + 4096 + c * 12288;
        int arow = wr * 16 + rsel;
        f16x8 af = *(const f16x8*)(As_ + arow * 64 + ((kb ^ ((arow >> 1) & 3)) << 4));
        if (ph == 0) {
#pragma unroll
            for (int gg = 0; gg < 3; ++gg)
#pragma unroll
                for (int nt = 0; nt < 2; ++nt) {
                    int brow = wc * 32 + nt * 16 + rsel;
                    f16x8 bf = *(const f16x8*)(Bs_ + (gg * 64 + brow) * 64 +
                                               ((kb ^ ((brow >> 1) & 3)) << 4));
                    acc1[gg][nt] = __builtin_amdgcn_mfma_f32_16x16x32_f16(af, bf, acc1[gg][nt], 0, 0, 0);
                }
        } else {
#pragma unroll
            for (int gg = 0; gg < 3; ++gg)
#pragma unroll
                for (int nt = 0; nt < 2; ++nt) {
                    int brow = wc * 32 + nt * 16 + rsel;
                    f16x8 bf = *(const f16x8*)(Bs_ + (gg * 64 + brow) * 64 +
                                               ((kb ^ ((brow >> 1) & 3)) << 4));
                    acc2[gg][nt] = __builtin_amdgcn_mfma_f32_16x16x32_f16(af, bf, acc2[gg][nt], 0, 0, 0);
                }
        }
    };

    GL0(0);
    GL1(1);
    LW0(0);
    __syncthreads();

    for (int i = 0; i < NT; i += 2) {
        if (i + 2 < NT) GL0(i + 2);
        COMP(0, (i < nk0) ? 0 : 1);
        LW1(1);
        __syncthreads();
        if (i + 3 < NT) GL1(i + 3);
        COMP(1, ((i + 1) < nk0) ? 0 : 1);
        if (i + 2 < NT) LW0(0);
        __syncthreads();
    }

    // ---- merge wave-group partials (red aliases stage smem; barrier-safe) ----
    f32x4* red = (f32x4*)smem;
    if (wg) {
#pragma unroll
        for (int g = 0; g < 3; ++g)
#pragma unroll
            for (int nt = 0; nt < 2; ++nt) red[ltid * 6 + g * 2 + nt] = acc1[g][nt];
    }
    __syncthreads();
    if (!wg) {
#pragma unroll
        for (int g = 0; g < 3; ++g)
#pragma unroll
            for (int nt = 0; nt < 2; ++nt) acc1[g][nt] += red[ltid * 6 + g * 2 + nt];
    }
    __syncthreads();
    if (wg) {
#pragma unroll
        for (int g = 0; g < 3; ++g)
#pragma unroll
            for (int nt = 0; nt < 2; ++nt) red[ltid * 6 + g * 2 + nt] = acc2[g][nt];
    }
    __syncthreads();

    if (!wg) {
#pragma unroll
        for (int g = 0; g < 3; ++g)
#pragma unroll
            for (int nt = 0; nt < 2; ++nt) acc2[g][nt] += red[ltid * 6 + g * 2 + nt];

#pragma unroll
        for (int nt = 0; nt < 2; ++nt) {
            int j = j0 + wc * 32 + nt * 16 + rsel;
            float br_i = bih[j],          br_h = bhh[j];
            float bz_i = bih[H_ + j],     bz_h = bhh[H_ + j];
            float bg_i = bih[2 * H_ + j], bg_h = bhh[2 * H_ + j];
#pragma unroll
            for (int q = 0; q < 4; ++q) {
                int row = b0 + wr * 16 + kb * 4 + q;
                float r = sigmoidf_(acc1[0][nt][q] + br_i + acc2[0][nt][q] + br_h);
                float z = sigmoidf_(acc1[1][nt][q] + bz_i + acc2[1][nt][q] + bz_h);
                float g = tanhf(acc1[2][nt][q] + bg_i + r * (acc2[2][nt][q] + bg_h));
                float leak;
                if (MODE == 0) leak = tg_cur[row] * h[(size_t)row * H_ + j];
                else           leak = h[(size_t)row * H_ + j];
                float hn = (1.f - z) * g + z * leak;
                h[(size_t)row * H_ + j] = hn;
                if (MODE == 0) {
                    out_a[(size_t)row * (N_ * H_) + j] = (f16)hn;
                    hs[(size_t)row * H_ + j] = (f16)(tg_next[row] * hn);
                } else {
                    out_a[(size_t)row * H_ + j] = (f16)hn;
                }
            }
        }
    }
}

// ---------------------------------------------------------------------------
// hw2 = h @ W2 (1024^3): 4-way split-K (1024 thr -> 16 waves/CU), 2-deep
// prefetch, 64x64 tile, f32 out. Grid (16,16) = 256 blocks = 1/CU.
// ---------------------------------------------------------------------------
__global__ __launch_bounds__(1024) void hgemm64_kernel(
    const f16* __restrict__ A, const f16* __restrict__ Bt, float* __restrict__ C)
{
    __shared__ char smem[65536];   // per wg 16KB: As[2]@0/4096, Bs[2]@8192/12288

    const int tid  = threadIdx.x;
    const int wg   = tid >> 8;       // 0..3
    const int ltid = tid & 255;
    const int lane = tid & 63;
    const int wid4 = (ltid >> 6);
    const int wr   = wid4 >> 1;
    const int wc   = wid4 & 1;
    const int rsel = lane & 15;
    const int kb   = lane >> 4;

    char* base = smem + wg * 16384;

    int flat = blockIdx.y * gridDim.x + blockIdx.x;   // grid (16,16)
    int nf   = (flat & 7) * 32 + (flat >> 3);
    const int m0 = (nf >> 4) * 64;
    const int n0 = (nf & 15) * 64;

    const int strow = ltid >> 2;
    const int sts   = ltid & 3;

    f32x4 acc[2][2];
#pragma unroll
    for (int m = 0; m < 2; ++m)
#pragma unroll
        for (int n = 0; n < 2; ++n) acc[m][n] = (f32x4)0.f;

    f16x8 sA, sB, tA, tB;
    auto GL0 = [&](int k0) {
        sA = *(const f16x8*)(A + (size_t)(m0 + strow) * H_ + k0 + sts * 8);
        sB = *(const f16x8*)(Bt + (size_t)(n0 + strow) * H_ + k0 + sts * 8);
    };
    auto GL1 = [&](int k0) {
        tA = *(const f16x8*)(A + (size_t)(m0 + strow) * H_ + k0 + sts * 8);
        tB = *(const f16x8*)(Bt + (size_t)(n0 + strow) * H_ + k0 + sts * 8);
    };
    auto LW0 = [&](int c) {
        lds_write_row((f16*)(base + c * 4096), strow, sts, sA);
        lds_write_row((f16*)(base + 8192 + c * 4096), strow, sts, sB);
    };
    auto LW1 = [&](int c) {
        lds_write_row((f16*)(base + c * 4096), strow, sts, tA);
        lds_write_row((f16*)(base + 8192 + c * 4096), strow, sts, tB);
    };
    auto COMP = [&](int c) {
        char* As_ = base + c * 4096;
        char* Bs_ = base + 8192 + c * 4096;
        f16x8 af[2], bf[2];
#pragma unroll
        for (int m = 0; m < 2; ++m) {
            int row = wr * 32 + m * 16 + rsel;
            af[m] = *(const f16x8*)(As_ + row * 64 + ((kb ^ ((row >> 1) & 3)) << 4));
        }
#pragma unroll
        for (int nt = 0; nt < 2; ++nt) {
            int row = wc * 32 + nt * 16 + rsel;
            bf[nt] = *(const f16x8*)(Bs_ + row * 64 + ((kb ^ ((row >> 1) & 3)) << 4));
        }
#pragma unroll
        for (int m = 0; m < 2; ++m)
#pragma unroll
            for (int nt = 0; nt < 2; ++nt)
                acc[m][nt] = __builtin_amdgcn_mfma_f32_16x16x32_f16(af[m], bf[nt], acc[m][nt], 0, 0, 0);
    };

    const int kbeg = wg * 256;      // K/4 per wave-group
    GL0(kbeg);
    GL1(kbeg + 32);
    LW0(0);
    __syncthreads();

    for (int ks = 0; ks < 8; ks += 2) {
        if (ks + 2 < 8) GL0(kbeg + (ks + 2) * 32);
        COMP(0);
        LW1(1);
        __syncthreads();
        if (ks + 3 < 8) GL1(kbeg + (ks + 3) * 32);
        COMP(1);
        if (ks + 2 < 8) LW0(0);
        __syncthreads();
    }

    // ---- 4-way reduction: wg1..3 dump partials (48KB), wg0 sums + writes ----
    f32x4* red = (f32x4*)smem;
    if (wg) {
#pragma unroll
        for (int m = 0; m < 2; ++m)
#pragma unroll
            for (int nt = 0; nt < 2; ++nt)
                red[((size_t)(wg - 1) * 256 + ltid) * 4 + m * 2 + nt] = acc[m][nt];
    }
    __syncthreads();
    if (!wg) {
#pragma unroll
        for (int m = 0; m < 2; ++m)
#pragma unroll
            for (int nt = 0; nt < 2; ++nt) {
#pragma unroll
                for (int w = 0; w < 3; ++w)
                    acc[m][nt] += red[((size_t)w * 256 + ltid) * 4 + m * 2 + nt];
                int col = n0 + wc * 32 + nt * 16 + rsel;
#pragma unroll
                for (int q = 0; q < 4; ++q) {
                    int row = m0 + wr * 32 + m * 16 + kb * 4 + q;
                    C[(size_t)row * H_ + col] = acc[m][nt][q];
                }
            }
    }
}

// ---------------------------------------------------------------------------
// Decoder init (fused): h/hs from gathered he, inp from init_token.
// ---------------------------------------------------------------------------
__global__ void dec_init_kernel(float* __restrict__ h, f16* __restrict__ hs,
                                const f16* __restrict__ he, const int* __restrict__ idx,
                                f16* __restrict__ inp, const float* __restrict__ tok)
{
    int i = blockIdx.x * blockDim.x + threadIdx.x;   // B*H
    int b = i >> 10;
    int j = i & (H_ - 1);
    float v0 = (float)he[(size_t)b * N_ * H_ + (size_t)idx[b * N_] * H_ + j];
    h[i]  = v0;
    hs[i] = (f16)v0;
    if (i < B_ * I_) inp[i] = (f16)tok[i & (I_ - 1)];
}

// ---------------------------------------------------------------------------
// Attention (+ next-step mix). One block per b, 1024 threads = 16 waves.
// ---------------------------------------------------------------------------
template <int MIX>
__global__ __launch_bounds__(1024) void attn_kernel(
    const f16*   __restrict__ w1xe,
    const float* __restrict__ hw2,
    const float* __restrict__ v,
    const float* __restrict__ phis,
    const f16*   __restrict__ in16,
    float* __restrict__ out,
    f16*   __restrict__ inp_step,
    int t,
    const float* __restrict__ tg_next,
    const int*   __restrict__ idx_next,
    const f16*   __restrict__ he,
    float* __restrict__ h,
    f16*   __restrict__ hs,
    const float* __restrict__ tok)
{
    int b   = blockIdx.x;
    int tid = threadIdx.x;
    int w   = tid >> 6;
    int l   = tid & 63;
    __shared__ float un[N_];
    __shared__ float attns[N_];

    {
        const f16*   wrow = w1xe + ((size_t)(b * N_ + w)) * H_;
        const float* hwp  = hw2 + (size_t)b * H_;
        f16x8 w0 = *(const f16x8*)(wrow + l * 8);
        f16x8 w1 = *(const f16x8*)(wrow + 512 + l * 8);
        f32x4 h0 = *(const f32x4*)(hwp + l * 8);
        f32x4 h1 = *(const f32x4*)(hwp + l * 8 + 4);
        f32x4 h2 = *(const f32x4*)(hwp + 512 + l * 8);
        f32x4 h3 = *(const f32x4*)(hwp + 512 + l * 8 + 4);
        f32x4 v0 = *(const f32x4*)(v + l * 8);
        f32x4 v1 = *(const f32x4*)(v + l * 8 + 4);
        f32x4 v2 = *(const f32x4*)(v + 512 + l * 8);
        f32x4 v3 = *(const f32x4*)(v + 512 + l * 8 + 4);
        float s = 0.f;
#pragma unroll
        for (int e = 0; e < 4; ++e) {
            s += tanhf((float)w0[e]     + h0[e]) * v0[e];
            s += tanhf((float)w0[e + 4] + h1[e]) * v1[e];
            s += tanhf((float)w1[e]     + h2[e]) * v2[e];
            s += tanhf((float)w1[e + 4] + h3[e]) * v3[e];
        }
#pragma unroll
        for (int off = 32; off; off >>= 1) s += __shfl_down(s, off, 64);
        if (l == 0) un[w] = s;
    }
    __syncthreads();

    if (tid < N_) {
        float mk = phis[(size_t)b * N_ * N_ + t * N_ + tid];
        float um = un[tid] * mk;
        float m = um;
#pragma unroll
        for (int off = 1; off < 16; off <<= 1) m = fmaxf(m, __shfl_xor(m, off, 16));
        float e = expf(um - m) * mk;
        float ssum = e;
#pragma unroll
        for (int off = 1; off < 16; off <<= 1) ssum += __shfl_xor(ssum, off, 16);
        float a = e / ssum;
        attns[tid] = a;
        out[(size_t)b * N_ * N_ + t * N_ + tid] = a;
    }
    __syncthreads();

    if (tid < I_) {
        float acc = 0.f;
#pragma unroll
        for (int n = 0; n < N_; ++n)
            acc += attns[n] * (float)in16[((size_t)b * N_ + n) * I_ + tid];
        if (MIX) {
            float tn = tg_next[b];
            inp_step[(size_t)b * I_ + tid] = (f16)(tn * acc + (1.f - tn) * tok[tid]);
        } else {
            inp_step[(size_t)b * I_ + tid] = (f16)acc;
        }
    }

    if (MIX) {
        float tn = tg_next[b];
        int id = idx_next[b * N_];
        float ih = (float)he[(size_t)b * N_ * H_ + (size_t)id * H_ + tid];
        float hm = tn * h[(size_t)b * H_ + tid] + (1.f - tn) * ih;
        h[(size_t)b * H_ + tid]  = hm;
        hs[(size_t)b * H_ + tid] = (f16)hm;
    }
}

// ---------------------------------------------------------------------------
// Launcher
// ---------------------------------------------------------------------------
extern "C" void kernel_launch(void* const* d_in, const int* in_sizes, int n_in,
                              void* d_out, int out_size, void* d_ws, size_t ws_size,
                              hipStream_t stream)
{
    const float* input      = (const float*)d_in[0];
    const float* phis       = (const float*)d_in[1];
    const float* init_token = (const float*)d_in[2];
    const float* W1         = (const float*)d_in[3];
    const float* W2         = (const float*)d_in[4];
    const float* v          = (const float*)d_in[5];
    const float* Wih_e      = (const float*)d_in[6];
    const float* Whh_e      = (const float*)d_in[7];
    const float* bih_e      = (const float*)d_in[8];
    const float* bhh_e      = (const float*)d_in[9];
    const float* Wih_d      = (const float*)d_in[10];
    const float* Whh_d      = (const float*)d_in[11];
    const float* bih_d      = (const float*)d_in[12];
    const float* bhh_d      = (const float*)d_in[13];
    float* out = (float*)d_out;

    char* p = (char*)d_ws;
    f16*  he16    = (f16*)p;  p += (size_t)B_ * N_ * H_ * 2;
    f16*  w1xe16  = (f16*)p;  p += (size_t)B_ * N_ * H_ * 2;
    float* h      = (float*)p; p += (size_t)B_ * H_ * 4;
    f16*  hs16    = (f16*)p;  p += (size_t)2 * B_ * H_ * 2;   // double-buffered (r10 race fix)
    f16*  hc16    = (f16*)p;  p += (size_t)B_ * H_ * 2;
    f16*  inp16   = (f16*)p;  p += (size_t)B_ * I_ * 2;
    float* hw2    = (float*)p; p += (size_t)B_ * H_ * 4;
    f16*  in16    = (f16*)p;  p += (size_t)B_ * N_ * I_ * 2;
    f16*  Wih_e16 = (f16*)p;  p += (size_t)H3_ * I_ * 2;
    f16*  Whh_e16 = (f16*)p;  p += (size_t)H3_ * H_ * 2;
    f16*  Wih_d16 = (f16*)p;  p += (size_t)H3_ * I_ * 2;
    f16*  Whh_d16 = (f16*)p;  p += (size_t)H3_ * H_ * 2;
    f16*  W1t16   = (f16*)p;  p += (size_t)H_ * H_ * 2;
    f16*  W2t16   = (f16*)p;  p += (size_t)H_ * H_ * 2;
    float* tg     = (float*)p; p += (size_t)17 * B_ * 4;
    int*   idx    = (int*)p;   p += (size_t)B_ * N_ * 4;

    const size_t BH = (size_t)B_ * H_;
    const int BHBLK = (B_ * H_) / 256;
    const dim3 gru_grid(16, 32);

    precompute_kernel<<<4, 256, 0, stream>>>(phis, tg, idx);

    cast_kernel<<<(B_ * N_ * I_) / 256, 256, 0, stream>>>(input, in16, B_ * N_ * I_);
    cast4_kernel<<<(2 * (H3_ * I_ + H3_ * H_)) / 256, 256, 0, stream>>>(
        Wih_e, Wih_e16, H3_ * I_, Whh_e, Whh_e16, H3_ * H_,
        Wih_d, Wih_d16, H3_ * I_, Whh_d, Whh_d16, H3_ * H_);
    transpose_cast2_kernel<<<dim3(32, 32, 2), 256, 0, stream>>>(W1, W1t16, W2, W2t16);

    // ---------------- encoder ----------------
    // hs double-buffered: step t READS hs16[t&1], WRITES hs16[(t+1)&1].
    hipMemsetAsync(h, 0, BH * 4, stream);
    hipMemsetAsync(hs16, 0, BH * 2, stream);
    for (int t = 0; t < N_; ++t) {
        gru_fused_kernel<0><<<gru_grid, 512, 0, stream>>>(
            in16 + (size_t)t * I_, N_ * I_, Wih_e16, I_, I_,
            hs16 + (size_t)(t & 1) * BH, Whh_e16, bih_e, bhh_e, h,
            tg + (size_t)t * B_, tg + (size_t)(t + 1) * B_,
            he16 + (size_t)t * H_, hs16 + (size_t)((t + 1) & 1) * BH);
    }

    // ---------------- W1xe = he @ W1 (f16 out) ----------------
    hgemm_kernel<f16><<<dim3(H_ / 128, (B_ * N_) / 128), 256, 0, stream>>>(
        he16, H_, W1t16, H_, w1xe16, H_, H_);

    // ---------------- decoder (hs buffer 0; gru<1> never writes hs) ----------
    dec_init_kernel<<<BHBLK, 256, 0, stream>>>(h, hs16, he16, idx, inp16, init_token);
    for (int t = 0; t < N_; ++t) {
        gru_fused_kernel<1><<<gru_grid, 512, 0, stream>>>(
            inp16, I_, Wih_d16, I_, I_,
            hs16, Whh_d16, bih_d, bhh_d, h,
            nullptr, nullptr, hc16, nullptr);
        hgemm64_kernel<<<dim3(16, 16), 1024, 0, stream>>>(hc16, W2t16, hw2);
        if (t < N_ - 1)
            attn_kernel<1><<<B_, 1024, 0, stream>>>(
                w1xe16, hw2, v, phis, in16, out, inp16, t,
                tg + (size_t)(t + 1) * B_, idx + (t + 1), he16, h, hs16, init_token);
        else
            attn_kernel<0><<<B_, 1024, 0, stream>>>(
                w1xe16, hw2, v, phis, in16, out, inp16, t,
                tg, idx, he16, h, hs16, init_token);
    }
}

// Round 13
// 1274.040 us; speedup vs baseline: 1.4951x; 1.4951x over previous
//
#include <hip/hip_runtime.h>
#include <math.h>

#define B_  1024
#define N_  16
#define I_  256
#define H_  1024
#define H3_ 3072

typedef _Float16 f16;
typedef _Float16 f16x4 __attribute__((ext_vector_type(4)));
typedef _Float16 f16x8 __attribute__((ext_vector_type(8)));
typedef float    f32x4 __attribute__((ext_vector_type(4)));

__device__ __forceinline__ float sigmoidf_(float x) { return 1.f / (1.f + expf(-x)); }

// LDS layout (verified r3): row = 64B = 4 groups of 16B; group g holds
// k = {4g..4g+3, 16+4g..16+4g+3}; XOR swizzle by ((row>>1)&3).
__device__ __forceinline__ void lds_write_row(f16* dst, int row, int s, f16x8 vv)
{
    int key = (row >> 1) & 3;
    int g0  = (((s & 1) * 2 + 0) ^ key);
    int g1  = (((s & 1) * 2 + 1) ^ key);
    f16x4 lo = {vv[0], vv[1], vv[2], vv[3]};
    f16x4 hi = {vv[4], vv[5], vv[6], vv[7]};
    *(f16x4*)((char*)dst + row * 64 + g0 * 16 + (s >> 1) * 8) = lo;
    *(f16x4*)((char*)dst + row * 64 + g1 * 16 + (s >> 1) * 8) = hi;
}

// ---------------------------------------------------------------------------
// Precompute t_gate (17,B) and idx_seq (B,N)
// ---------------------------------------------------------------------------
__global__ void precompute_kernel(const float* __restrict__ phis,
                                  float* __restrict__ tg,
                                  int* __restrict__ idx)
{
    int b = blockIdx.x * blockDim.x + threadIdx.x;
    if (b >= B_) return;
    tg[b] = 1.0f;
    for (int t = 1; t < N_; ++t)
        tg[t * B_ + b] = phis[(size_t)b * N_ * N_ + t * N_ + (t - 1)];
    tg[16 * B_ + b] = 0.0f;
    for (int t = 0; t < N_; ++t) {
        float ns = 0.f;
        for (int k = 0; k < N_; ++k) ns += phis[(size_t)b * N_ * N_ + t * N_ + k];
        int nsi = (int)(ns + 0.5f);
        idx[b * N_ + t] = (nsi + t - 1) % N_;
    }
}

// ---------------------------------------------------------------------------
// Casts
// ---------------------------------------------------------------------------
__global__ void cast_kernel(const float* __restrict__ in, f16* __restrict__ out, int n)
{
    int i = blockIdx.x * blockDim.x + threadIdx.x;
    if (i < n) out[i] = (f16)in[i];
}

__global__ void cast4_kernel(const float* __restrict__ s0, f16* __restrict__ d0, int n0,
                             const float* __restrict__ s1, f16* __restrict__ d1, int n1,
                             const float* __restrict__ s2, f16* __restrict__ d2, int n2,
                             const float* __restrict__ s3, f16* __restrict__ d3, int n3)
{
    int i = blockIdx.x * blockDim.x + threadIdx.x;
    int T0 = n0, T1 = T0 + n1, T2 = T1 + n2, T3 = T2 + n3;
    if (i < T0) d0[i] = (f16)s0[i];
    else if (i < T1) d1[i - T0] = (f16)s1[i - T0];
    else if (i < T2) d2[i - T1] = (f16)s2[i - T1];
    else if (i < T3) d3[i - T2] = (f16)s3[i - T2];
}

__global__ __launch_bounds__(256) void transpose_cast2_kernel(
    const float* __restrict__ in0, f16* __restrict__ out0,
    const float* __restrict__ in1, f16* __restrict__ out1)
{
    const float* in  = blockIdx.z ? in1 : in0;
    f16*        outp = blockIdx.z ? out1 : out0;
    __shared__ float tile[32][33];
    int bx = blockIdx.x * 32, by = blockIdx.y * 32;
    int tx = threadIdx.x & 31, ty = threadIdx.x >> 5;
#pragma unroll
    for (int r = 0; r < 32; r += 8)
        tile[ty + r][tx] = in[(size_t)(by + ty + r) * H_ + bx + tx];
    __syncthreads();
#pragma unroll
    for (int r = 0; r < 32; r += 8)
        outp[(size_t)(bx + ty + r) * H_ + by + tx] = (f16)tile[tx][ty + r];
}

// ---------------------------------------------------------------------------
// 128x128 MFMA GEMM (W1xe): C = A @ Bt^T, f16 out, XCD-chunked swizzle.
// 2-deep prefetch pipeline: two register sets, dbuf LDS.
// ---------------------------------------------------------------------------
template <typename OutT>
__global__ __launch_bounds__(256) void hgemm_kernel(
    const f16* __restrict__ A, int lda,
    const f16* __restrict__ Bt, int ldb,
    OutT* __restrict__ C, int ldc, int K)
{
    __shared__ char smem[32768];   // As[2]@0/8192, Bs[2]@16384/24576

    const int tid  = threadIdx.x;
    const int lane = tid & 63;
    const int wid  = tid >> 6;
    const int wr   = wid >> 1;
    const int wc   = wid & 1;
    const int rsel = lane & 15;
    const int kb   = lane >> 4;

    int flat = blockIdx.y * gridDim.x + blockIdx.x;
    int nwg  = gridDim.x * gridDim.y;
    int cpx  = nwg >> 3;
    int nf   = (flat & 7) * cpx + (flat >> 3);
    const int n0 = (int)(nf % gridDim.x) * 128;
    const int m0 = (int)(nf / gridDim.x) * 128;

    const int strow0 = tid >> 2;
    const int strow1 = 64 + (tid >> 2);
    const int sts    = tid & 3;

    f32x4 acc[4][4];
#pragma unroll
    for (int m = 0; m < 4; ++m)
#pragma unroll
        for (int n = 0; n < 4; ++n) acc[m][n] = (f32x4)0.f;

    f16x8 sA0, sA1, sB0, sB1;   // set 0
    f16x8 tA0, tA1, tB0, tB1;   // set 1
    auto GL0 = [&](int k0) {
        sA0 = *(const f16x8*)(A + (size_t)(m0 + strow0) * lda + k0 + sts * 8);
        sA1 = *(const f16x8*)(A + (size_t)(m0 + strow1) * lda + k0 + sts * 8);
        sB0 = *(const f16x8*)(Bt + (size_t)(n0 + strow0) * ldb + k0 + sts * 8);
        sB1 = *(const f16x8*)(Bt + (size_t)(n0 + strow1) * ldb + k0 + sts * 8);
    };
    auto GL1 = [&](int k0) {
        tA0 = *(const f16x8*)(A + (size_t)(m0 + strow0) * lda + k0 + sts * 8);
        tA1 = *(const f16x8*)(A + (size_t)(m0 + strow1) * lda + k0 + sts * 8);
        tB0 = *(const f16x8*)(Bt + (size_t)(n0 + strow0) * ldb + k0 + sts * 8);
        tB1 = *(const f16x8*)(Bt + (size_t)(n0 + strow1) * ldb + k0 + sts * 8);
    };
    auto LW0 = [&](int c) {
        f16* As_ = (f16*)(smem + c * 8192);
        f16* Bs_ = (f16*)(smem + 16384 + c * 8192);
        lds_write_row(As_, strow0, sts, sA0);
        lds_write_row(As_, strow1, sts, sA1);
        lds_write_row(Bs_, strow0, sts, sB0);
        lds_write_row(Bs_, strow1, sts, sB1);
    };
    auto LW1 = [&](int c) {
        f16* As_ = (f16*)(smem + c * 8192);
        f16* Bs_ = (f16*)(smem + 16384 + c * 8192);
        lds_write_row(As_, strow0, sts, tA0);
        lds_write_row(As_, strow1, sts, tA1);
        lds_write_row(Bs_, strow0, sts, tB0);
        lds_write_row(Bs_, strow1, sts, tB1);
    };
    auto COMP = [&](int c) {
        char* As_ = smem + c * 8192;
        char* Bs_ = smem + 16384 + c * 8192;
        f16x8 af[4], bf[4];
#pragma unroll
        for (int m = 0; m < 4; ++m) {
            int row = wr * 64 + m * 16 + rsel;
            af[m] = *(const f16x8*)(As_ + row * 64 + ((kb ^ ((row >> 1) & 3)) << 4));
        }
#pragma unroll
        for (int n = 0; n < 4; ++n) {
            int row = wc * 64 + n * 16 + rsel;
            bf[n] = *(const f16x8*)(Bs_ + row * 64 + ((kb ^ ((row >> 1) & 3)) << 4));
        }
#pragma unroll
        for (int m = 0; m < 4; ++m)
#pragma unroll
            for (int n = 0; n < 4; ++n)
                acc[m][n] = __builtin_amdgcn_mfma_f32_16x16x32_f16(af[m], bf[n], acc[m][n], 0, 0, 0);
    };

    const int nk = K / 32;   // even
    GL0(0);
    GL1(32);
    LW0(0);
    __syncthreads();

    for (int ks = 0; ks < nk; ks += 2) {
        if (ks + 2 < nk) GL0((ks + 2) * 32);
        COMP(0);
        LW1(1);
        __syncthreads();
        if (ks + 3 < nk) GL1((ks + 3) * 32);
        COMP(1);
        if (ks + 2 < nk) LW0(0);
        __syncthreads();
    }

#pragma unroll
    for (int m = 0; m < 4; ++m) {
        int row0 = m0 + wr * 64 + m * 16 + kb * 4;
#pragma unroll
        for (int n = 0; n < 4; ++n) {
            int col = n0 + wc * 64 + n * 16 + rsel;
#pragma unroll
            for (int r = 0; r < 4; ++r)
                C[(size_t)(row0 + r) * ldc + col] = (OutT)acc[m][n][r];
        }
    }
}

// ---------------------------------------------------------------------------
// Fused GEMM + GRU (r11 structure: 32b x 64j, grid 16x32, split-K 2 wg,
// TWO SEPARATE fully-unrolled phase pipelines). K1/ldb1 are compile-time
// (I_=256) so phase-0 unrolls completely.
// NOTE: encoder must pass DIFFERENT buffers for A2 (read) and hs (write) —
// r10 race.
// ---------------------------------------------------------------------------
template <int MODE>
__global__ __launch_bounds__(512) void gru_fused_kernel(
    const f16* __restrict__ A1, int lda1,
    const f16* __restrict__ Bt1,
    const f16* __restrict__ A2,
    const f16* __restrict__ Bt2,
    const float* __restrict__ bih, const float* __restrict__ bhh,
    float* __restrict__ h,
    const float* __restrict__ tg_cur,
    const float* __restrict__ tg_next,
    f16* __restrict__ out_a,
    f16* __restrict__ hs)
{
    __shared__ char smem[57344];

    const int tid  = threadIdx.x;
    const int wg   = tid >> 8;
    const int ltid = tid & 255;
    const int lane = tid & 63;
    const int wid4 = (ltid >> 6);
    const int wr   = wid4 >> 1;
    const int wc   = wid4 & 1;
    const int rsel = lane & 15;
    const int kb   = lane >> 4;

    char* base = smem + wg * 28672;   // As[c]@ c*2048, Bs[c]@ 4096 + c*12288

    int flat = blockIdx.y * gridDim.x + blockIdx.x;   // grid (16, 32)
    int nf   = (flat & 7) * 64 + (flat >> 3);
    const int j0 = (nf >> 5) * 64;
    const int b0 = (nf & 31) * 32;

    const int strow = ltid >> 2;
    const int sts   = ltid & 3;

    f32x4 acc1[3][2], acc2[3][2];
#pragma unroll
    for (int g = 0; g < 3; ++g)
#pragma unroll
        for (int nt = 0; nt < 2; ++nt) { acc1[g][nt] = (f32x4)0.f; acc2[g][nt] = (f32x4)0.f; }

    f16x8 sA, sB0, sB1, sB2;
    f16x8 tA, tB0, tB1, tB2;
    const f16* Ap;  const f16* Btp;  int ldap, ldbp;
    auto GL0 = [&](int k0) {
        if (ltid < 128) sA = *(const f16x8*)(Ap + (size_t)(b0 + strow) * ldap + k0 + sts * 8);
        sB0 = *(const f16x8*)(Btp + (size_t)(0 * H_ + j0 + strow) * ldbp + k0 + sts * 8);
        sB1 = *(const f16x8*)(Btp + (size_t)(1 * H_ + j0 + strow) * ldbp + k0 + sts * 8);
        sB2 = *(const f16x8*)(Btp + (size_t)(2 * H_ + j0 + strow) * ldbp + k0 + sts * 8);
    };
    auto GL1 = [&](int k0) {
        if (ltid < 128) tA = *(const f16x8*)(Ap + (size_t)(b0 + strow) * ldap + k0 + sts * 8);
        tB0 = *(const f16x8*)(Btp + (size_t)(0 * H_ + j0 + strow) * ldbp + k0 + sts * 8);
        tB1 = *(const f16x8*)(Btp + (size_t)(1 * H_ + j0 + strow) * ldbp + k0 + sts * 8);
        tB2 = *(const f16x8*)(Btp + (size_t)(2 * H_ + j0 + strow) * ldbp + k0 + sts * 8);
    };
    auto LW0 = [&](int c) {
        if (ltid < 128) lds_write_row((f16*)(base + c * 2048), strow, sts, sA);
        f16* Bs_ = (f16*)(base + 4096 + c * 12288);
        lds_write_row(Bs_ + 0 * 64 * 32, strow, sts, sB0);
        lds_write_row(Bs_ + 1 * 64 * 32, strow, sts, sB1);
        lds_write_row(Bs_ + 2 * 64 * 32, strow, sts, sB2);
    };
    auto LW1 = [&](int c) {
        if (ltid < 128) lds_write_row((f16*)(base + c * 2048), strow, sts, tA);
        f16* Bs_ = (f16*)(base + 4096 + c * 12288);
        lds_write_row(Bs_ + 0 * 64 * 32, strow, sts, tB0);
        lds_write_row(Bs_ + 1 * 64 * 32, strow, sts, tB1);
        lds_write_row(Bs_ + 2 * 64 * 32, strow, sts, tB2);
    };
    auto COMP = [&](int c, int phase) {
        char* As_ = base + c * 2048;
        char* Bs_ = base + 4096 + c * 12288;
        int arow = wr * 16 + rsel;
        f16x8 af = *(const f16x8*)(As_ + arow * 64 + ((kb ^ ((arow >> 1) & 3)) << 4));
#pragma unroll
        for (int gg = 0; gg < 3; ++gg)
#pragma unroll
            for (int nt = 0; nt < 2; ++nt) {
                int brow = wc * 32 + nt * 16 + rsel;
                f16x8 bf = *(const f16x8*)(Bs_ + (gg * 64 + brow) * 64 +
                                           ((kb ^ ((brow >> 1) & 3)) << 4));
                if (phase == 0)
                    acc1[gg][nt] = __builtin_amdgcn_mfma_f32_16x16x32_f16(af, bf, acc1[gg][nt], 0, 0, 0);
                else
                    acc2[gg][nt] = __builtin_amdgcn_mfma_f32_16x16x32_f16(af, bf, acc2[gg][nt], 0, 0, 0);
            }
    };

#pragma unroll
    for (int phase = 0; phase < 2; ++phase) {
        Ap   = phase ? A2 : A1;
        Btp  = phase ? Bt2 : Bt1;
        ldap = phase ? H_ : lda1;
        ldbp = phase ? H_ : I_;            // compile-time ldb for phase 0
        const int Kp   = phase ? H_ : I_;  // compile-time K
        const int half = Kp >> 1;
        const int kbeg = wg * half;
        const int nk   = half >> 5;        // 4 or 16 (compile-time)

        GL0(kbeg);
        GL1(kbeg + 32);
        LW0(0);
        __syncthreads();

#pragma unroll
        for (int ks = 0; ks < nk; ks += 2) {
            if (ks + 2 < nk) GL0(kbeg + (ks + 2) * 32);
            COMP(0, phase);
            LW1(1);
            __syncthreads();
            if (ks + 3 < nk) GL1(kbeg + (ks + 3) * 32);
            COMP(1, phase);
            if (ks + 2 < nk) LW0(0);
            __syncthreads();
        }
    }

    // ---- merge wave-group partials (red aliases stage smem; barrier-safe) ----
    f32x4* red = (f32x4*)smem;
    if (wg) {
#pragma unroll
        for (int g = 0; g < 3; ++g)
#pragma unroll
            for (int nt = 0; nt < 2; ++nt) red[ltid * 6 + g * 2 + nt] = acc1[g][nt];
    }
    __syncthreads();
    if (!wg) {
#pragma unroll
        for (int g = 0; g < 3; ++g)
#pragma unroll
            for (int nt = 0; nt < 2; ++nt) acc1[g][nt] += red[ltid * 6 + g * 2 + nt];
    }
    __syncthreads();
    if (wg) {
#pragma unroll
        for (int g = 0; g < 3; ++g)
#pragma unroll
            for (int nt = 0; nt < 2; ++nt) red[ltid * 6 + g * 2 + nt] = acc2[g][nt];
    }
    __syncthreads();

    if (!wg) {
#pragma unroll
        for (int g = 0; g < 3; ++g)
#pragma unroll
            for (int nt = 0; nt < 2; ++nt) acc2[g][nt] += red[ltid * 6 + g * 2 + nt];

#pragma unroll
        for (int nt = 0; nt < 2; ++nt) {
            int j = j0 + wc * 32 + nt * 16 + rsel;
            float br_i = bih[j],          br_h = bhh[j];
            float bz_i = bih[H_ + j],     bz_h = bhh[H_ + j];
            float bg_i = bih[2 * H_ + j], bg_h = bhh[2 * H_ + j];
#pragma unroll
            for (int q = 0; q < 4; ++q) {
                int row = b0 + wr * 16 + kb * 4 + q;
                float r = sigmoidf_(acc1[0][nt][q] + br_i + acc2[0][nt][q] + br_h);
                float z = sigmoidf_(acc1[1][nt][q] + bz_i + acc2[1][nt][q] + bz_h);
                float g = tanhf(acc1[2][nt][q] + bg_i + r * (acc2[2][nt][q] + bg_h));
                float leak;
                if (MODE == 0) leak = tg_cur[row] * h[(size_t)row * H_ + j];
                else           leak = h[(size_t)row * H_ + j];
                float hn = (1.f - z) * g + z * leak;
                h[(size_t)row * H_ + j] = hn;
                if (MODE == 0) {
                    out_a[(size_t)row * (N_ * H_) + j] = (f16)hn;
                    hs[(size_t)row * H_ + j] = (f16)(tg_next[row] * hn);
                } else {
                    out_a[(size_t)row * H_ + j] = (f16)hn;
                }
            }
        }
    }
}

// ---------------------------------------------------------------------------
// hw2 = h @ W2 (1024^3): r11 structure — split-K (2 wg) + 2-deep prefetch,
// 64x64 tile, 512 threads, f32 out.
// ---------------------------------------------------------------------------
__global__ __launch_bounds__(512) void hgemm64_kernel(
    const f16* __restrict__ A, const f16* __restrict__ Bt, float* __restrict__ C)
{
    __shared__ char smem[32768];

    const int tid  = threadIdx.x;
    const int wg   = tid >> 8;
    const int ltid = tid & 255;
    const int lane = tid & 63;
    const int wid4 = (ltid >> 6);
    const int wr   = wid4 >> 1;
    const int wc   = wid4 & 1;
    const int rsel = lane & 15;
    const int kb   = lane >> 4;

    char* base = smem + wg * 16384;

    int flat = blockIdx.y * gridDim.x + blockIdx.x;
    int nf   = (flat & 7) * 32 + (flat >> 3);
    const int m0 = (nf >> 4) * 64;
    const int n0 = (nf & 15) * 64;

    const int strow = ltid >> 2;
    const int sts   = ltid & 3;

    f32x4 acc[2][2];
#pragma unroll
    for (int m = 0; m < 2; ++m)
#pragma unroll
        for (int n = 0; n < 2; ++n) acc[m][n] = (f32x4)0.f;

    f16x8 sA, sB, tA, tB;
    auto GL0 = [&](int k0) {
        sA = *(const f16x8*)(A + (size_t)(m0 + strow) * H_ + k0 + sts * 8);
        sB = *(const f16x8*)(Bt + (size_t)(n0 + strow) * H_ + k0 + sts * 8);
    };
    auto GL1 = [&](int k0) {
        tA = *(const f16x8*)(A + (size_t)(m0 + strow) * H_ + k0 + sts * 8);
        tB = *(const f16x8*)(Bt + (size_t)(n0 + strow) * H_ + k0 + sts * 8);
    };
    auto LW0 = [&](int c) {
        lds_write_row((f16*)(base + c * 4096), strow, sts, sA);
        lds_write_row((f16*)(base + 8192 + c * 4096), strow, sts, sB);
    };
    auto LW1 = [&](int c) {
        lds_write_row((f16*)(base + c * 4096), strow, sts, tA);
        lds_write_row((f16*)(base + 8192 + c * 4096), strow, sts, tB);
    };
    auto COMP = [&](int c) {
        char* As_ = base + c * 4096;
        char* Bs_ = base + 8192 + c * 4096;
        f16x8 af[2], bf[2];
#pragma unroll
        for (int m = 0; m < 2; ++m) {
            int row = wr * 32 + m * 16 + rsel;
            af[m] = *(const f16x8*)(As_ + row * 64 + ((kb ^ ((row >> 1) & 3)) << 4));
        }
#pragma unroll
        for (int nt = 0; nt < 2; ++nt) {
            int row = wc * 32 + nt * 16 + rsel;
            bf[nt] = *(const f16x8*)(Bs_ + row * 64 + ((kb ^ ((row >> 1) & 3)) << 4));
        }
#pragma unroll
        for (int m = 0; m < 2; ++m)
#pragma unroll
            for (int nt = 0; nt < 2; ++nt)
                acc[m][nt] = __builtin_amdgcn_mfma_f32_16x16x32_f16(af[m], bf[nt], acc[m][nt], 0, 0, 0);
    };

    const int kbeg = wg * 512;
    GL0(kbeg);
    GL1(kbeg + 32);
    LW0(0);
    __syncthreads();

#pragma unroll
    for (int ks = 0; ks < 16; ks += 2) {
        if (ks + 2 < 16) GL0(kbeg + (ks + 2) * 32);
        COMP(0);
        LW1(1);
        __syncthreads();
        if (ks + 3 < 16) GL1(kbeg + (ks + 3) * 32);
        COMP(1);
        if (ks + 2 < 16) LW0(0);
        __syncthreads();
    }

    f32x4* red = (f32x4*)smem;
    if (wg) {
#pragma unroll
        for (int m = 0; m < 2; ++m)
#pragma unroll
            for (int nt = 0; nt < 2; ++nt) red[ltid * 4 + m * 2 + nt] = acc[m][nt];
    }
    __syncthreads();
    if (!wg) {
#pragma unroll
        for (int m = 0; m < 2; ++m)
#pragma unroll
            for (int nt = 0; nt < 2; ++nt) {
                acc[m][nt] += red[ltid * 4 + m * 2 + nt];
                int col = n0 + wc * 32 + nt * 16 + rsel;
#pragma unroll
                for (int q = 0; q < 4; ++q) {
                    int row = m0 + wr * 32 + m * 16 + kb * 4 + q;
                    C[(size_t)row * H_ + col] = acc[m][nt][q];
                }
            }
    }
}

// ---------------------------------------------------------------------------
// Decoder init (fused): h/hs from gathered he, inp from init_token.
// ---------------------------------------------------------------------------
__global__ void dec_init_kernel(float* __restrict__ h, f16* __restrict__ hs,
                                const f16* __restrict__ he, const int* __restrict__ idx,
                                f16* __restrict__ inp, const float* __restrict__ tok)
{
    int i = blockIdx.x * blockDim.x + threadIdx.x;   // B*H
    int b = i >> 10;
    int j = i & (H_ - 1);
    float v0 = (float)he[(size_t)b * N_ * H_ + (size_t)idx[b * N_] * H_ + j];
    h[i]  = v0;
    hs[i] = (f16)v0;
    if (i < B_ * I_) inp[i] = (f16)tok[i & (I_ - 1)];
}

// ---------------------------------------------------------------------------
// Attention (+ next-step mix). One block per b, 1024 threads = 16 waves.
// ---------------------------------------------------------------------------
template <int MIX>
__global__ __launch_bounds__(1024) void attn_kernel(
    const f16*   __restrict__ w1xe,
    const float* __restrict__ hw2,
    const float* __restrict__ v,
    const float* __restrict__ phis,
    const f16*   __restrict__ in16,
    float* __restrict__ out,
    f16*   __restrict__ inp_step,
    int t,
    const float* __restrict__ tg_next,
    const int*   __restrict__ idx_next,
    const f16*   __restrict__ he,
    float* __restrict__ h,
    f16*   __restrict__ hs,
    const float* __restrict__ tok)
{
    int b   = blockIdx.x;
    int tid = threadIdx.x;
    int w   = tid >> 6;
    int l   = tid & 63;
    __shared__ float un[N_];
    __shared__ float attns[N_];

    {
        const f16*   wrow = w1xe + ((size_t)(b * N_ + w)) * H_;
        const float* hwp  = hw2 + (size_t)b * H_;
        f16x8 w0 = *(const f16x8*)(wrow + l * 8);
        f16x8 w1 = *(const f16x8*)(wrow + 512 + l * 8);
        f32x4 h0 = *(const f32x4*)(hwp + l * 8);
        f32x4 h1 = *(const f32x4*)(hwp + l * 8 + 4);
        f32x4 h2 = *(const f32x4*)(hwp + 512 + l * 8);
        f32x4 h3 = *(const f32x4*)(hwp + 512 + l * 8 + 4);
        f32x4 v0 = *(const f32x4*)(v + l * 8);
        f32x4 v1 = *(const f32x4*)(v + l * 8 + 4);
        f32x4 v2 = *(const f32x4*)(v + 512 + l * 8);
        f32x4 v3 = *(const f32x4*)(v + 512 + l * 8 + 4);
        float s = 0.f;
#pragma unroll
        for (int e = 0; e < 4; ++e) {
            s += tanhf((float)w0[e]     + h0[e]) * v0[e];
            s += tanhf((float)w0[e + 4] + h1[e]) * v1[e];
            s += tanhf((float)w1[e]     + h2[e]) * v2[e];
            s += tanhf((float)w1[e + 4] + h3[e]) * v3[e];
        }
#pragma unroll
        for (int off = 32; off; off >>= 1) s += __shfl_down(s, off, 64);
        if (l == 0) un[w] = s;
    }
    __syncthreads();

    if (tid < N_) {
        float mk = phis[(size_t)b * N_ * N_ + t * N_ + tid];
        float um = un[tid] * mk;
        float m = um;
#pragma unroll
        for (int off = 1; off < 16; off <<= 1) m = fmaxf(m, __shfl_xor(m, off, 16));
        float e = expf(um - m) * mk;
        float ssum = e;
#pragma unroll
        for (int off = 1; off < 16; off <<= 1) ssum += __shfl_xor(ssum, off, 16);
        float a = e / ssum;
        attns[tid] = a;
        out[(size_t)b * N_ * N_ + t * N_ + tid] = a;
    }
    __syncthreads();

    if (tid < I_) {
        float acc = 0.f;
#pragma unroll
        for (int n = 0; n < N_; ++n)
            acc += attns[n] * (float)in16[((size_t)b * N_ + n) * I_ + tid];
        if (MIX) {
            float tn = tg_next[b];
            inp_step[(size_t)b * I_ + tid] = (f16)(tn * acc + (1.f - tn) * tok[tid]);
        } else {
            inp_step[(size_t)b * I_ + tid] = (f16)acc;
        }
    }

    if (MIX) {
        float tn = tg_next[b];
        int id = idx_next[b * N_];
        float ih = (float)he[(size_t)b * N_ * H_ + (size_t)id * H_ + tid];
        float hm = tn * h[(size_t)b * H_ + tid] + (1.f - tn) * ih;
        h[(size_t)b * H_ + tid]  = hm;
        hs[(size_t)b * H_ + tid] = (f16)hm;
    }
}

// ---------------------------------------------------------------------------
// Launcher
// ---------------------------------------------------------------------------
extern "C" void kernel_launch(void* const* d_in, const int* in_sizes, int n_in,
                              void* d_out, int out_size, void* d_ws, size_t ws_size,
                              hipStream_t stream)
{
    const float* input      = (const float*)d_in[0];
    const float* phis       = (const float*)d_in[1];
    const float* init_token = (const float*)d_in[2];
    const float* W1         = (const float*)d_in[3];
    const float* W2         = (const float*)d_in[4];
    const float* v          = (const float*)d_in[5];
    const float* Wih_e      = (const float*)d_in[6];
    const float* Whh_e      = (const float*)d_in[7];
    const float* bih_e      = (const float*)d_in[8];
    const float* bhh_e      = (const float*)d_in[9];
    const float* Wih_d      = (const float*)d_in[10];
    const float* Whh_d      = (const float*)d_in[11];
    const float* bih_d      = (const float*)d_in[12];
    const float* bhh_d      = (const float*)d_in[13];
    float* out = (float*)d_out;

    char* p = (char*)d_ws;
    f16*  he16    = (f16*)p;  p += (size_t)B_ * N_ * H_ * 2;
    f16*  w1xe16  = (f16*)p;  p += (size_t)B_ * N_ * H_ * 2;
    float* h      = (float*)p; p += (size_t)B_ * H_ * 4;
    f16*  hs16    = (f16*)p;  p += (size_t)2 * B_ * H_ * 2;   // double-buffered (r10 race fix)
    f16*  hc16    = (f16*)p;  p += (size_t)B_ * H_ * 2;
    f16*  inp16   = (f16*)p;  p += (size_t)B_ * I_ * 2;
    float* hw2    = (float*)p; p += (size_t)B_ * H_ * 4;
    f16*  in16    = (f16*)p;  p += (size_t)B_ * N_ * I_ * 2;
    f16*  Wih_e16 = (f16*)p;  p += (size_t)H3_ * I_ * 2;
    f16*  Whh_e16 = (f16*)p;  p += (size_t)H3_ * H_ * 2;
    f16*  Wih_d16 = (f16*)p;  p += (size_t)H3_ * I_ * 2;
    f16*  Whh_d16 = (f16*)p;  p += (size_t)H3_ * H_ * 2;
    f16*  W1t16   = (f16*)p;  p += (size_t)H_ * H_ * 2;
    f16*  W2t16   = (f16*)p;  p += (size_t)H_ * H_ * 2;
    float* tg     = (float*)p; p += (size_t)17 * B_ * 4;
    int*   idx    = (int*)p;   p += (size_t)B_ * N_ * 4;

    const size_t BH = (size_t)B_ * H_;
    const int BHBLK = (B_ * H_) / 256;
    const dim3 gru_grid(16, 32);

    precompute_kernel<<<4, 256, 0, stream>>>(phis, tg, idx);

    cast_kernel<<<(B_ * N_ * I_) / 256, 256, 0, stream>>>(input, in16, B_ * N_ * I_);
    cast4_kernel<<<(2 * (H3_ * I_ + H3_ * H_)) / 256, 256, 0, stream>>>(
        Wih_e, Wih_e16, H3_ * I_, Whh_e, Whh_e16, H3_ * H_,
        Wih_d, Wih_d16, H3_ * I_, Whh_d, Whh_d16, H3_ * H_);
    transpose_cast2_kernel<<<dim3(32, 32, 2), 256, 0, stream>>>(W1, W1t16, W2, W2t16);

    // ---------------- encoder ----------------
    // hs double-buffered: step t READS hs16[t&1], WRITES hs16[(t+1)&1].
    hipMemsetAsync(h, 0, BH * 4, stream);
    hipMemsetAsync(hs16, 0, BH * 2, stream);
    for (int t = 0; t < N_; ++t) {
        gru_fused_kernel<0><<<gru_grid, 512, 0, stream>>>(
            in16 + (size_t)t * I_, N_ * I_, Wih_e16,
            hs16 + (size_t)(t & 1) * BH, Whh_e16, bih_e, bhh_e, h,
            tg + (size_t)t * B_, tg + (size_t)(t + 1) * B_,
            he16 + (size_t)t * H_, hs16 + (size_t)((t + 1) & 1) * BH);
    }

    // ---------------- W1xe = he @ W1 (f16 out) ----------------
    hgemm_kernel<f16><<<dim3(H_ / 128, (B_ * N_) / 128), 256, 0, stream>>>(
        he16, H_, W1t16, H_, w1xe16, H_, H_);

    // ---------------- decoder (hs buffer 0; gru<1> never writes hs) ----------
    dec_init_kernel<<<BHBLK, 256, 0, stream>>>(h, hs16, he16, idx, inp16, init_token);
    for (int t = 0; t < N_; ++t) {
        gru_fused_kernel<1><<<gru_grid, 512, 0, stream>>>(
            inp16, I_, Wih_d16,
            hs16, Whh_d16, bih_d, bhh_d, h,
            nullptr, nullptr, hc16, nullptr);
        hgemm64_kernel<<<dim3(16, 16), 512, 0, stream>>>(hc16, W2t16, hw2);
        if (t < N_ - 1)
            attn_kernel<1><<<B_, 1024, 0, stream>>>(
                w1xe16, hw2, v, phis, in16, out, inp16, t,
                tg + (size_t)(t + 1) * B_, idx + (t + 1), he16, h, hs16, init_token);
        else
            attn_kernel<0><<<B_, 1024, 0, stream>>>(
                w1xe16, hw2, v, phis, in16, out, inp16, t,
                tg, idx, he16, h, hs16, init_token);
    }
}